// Round 4
// baseline (83.866 us; speedup 1.0000x reference)
//
#include <hip/hip_runtime.h>
#include <hip/hip_bf16.h>

#define N_NODES 100000
#define DEG 16
#define D 128

typedef __bf16 bf16x8 __attribute__((ext_vector_type(8)));
typedef float f32x4 __attribute__((ext_vector_type(4)));

__device__ __forceinline__ unsigned pk2(float a, float b) {
  union { __bf16 h[2]; unsigned u; } x;
  x.h[0] = (__bf16)a; x.h[1] = (__bf16)b;
  return x.u;
}

// swizzled element index into a [128][128] ushort LDS tile (XOR bits 3..5 of k with row bits 0..2)
__device__ __forceinline__ int swz(int row, int k) {
  return (row << 7) + (k ^ ((row & 7) << 3));
}

// Kernel 0: W [k][n] f32 -> Wt bf16 transposed [n][k], swizzled (64 blocks, 1 elem/thread)
__global__ void k_convW(const float* __restrict__ W, ushort* __restrict__ Wt) {
  int pos = (blockIdx.x << 8) + threadIdx.x;   // 0..16383
  int k = pos >> 7, n = pos & 127;
  union { __bf16 h; ushort u; } c;
  c.h = (__bf16)W[pos];
  Wt[swz(n, k)] = c.u;
}

// Kernel 1: Xp = bf16(X @ W), rows stored in permuted col order: pos p=llo*8+n <-> col n*16+llo.
// 128-row tile per block, 4 waves, A-fragments loaded direct from global (no A LDS).
__global__ __launch_bounds__(256, 2) void k_gemm(const float* __restrict__ X,
                                                 const ushort* __restrict__ Wt,
                                                 ushort* __restrict__ Xp) {
  __shared__ __align__(16) ushort Ws[128 * 128];
  const int tid = threadIdx.x;
  const int row0 = blockIdx.x << 7;
  const int wave = tid >> 6;
  const int lane = tid & 63;
  const int lhi = lane >> 4;           // 0..3
  const int llo = lane & 15;

  // stage pre-swizzled Wt (32 KB linear copy)
  {
    const uint4* src = (const uint4*)Wt;
    uint4* dst = (uint4*)Ws;
#pragma unroll
    for (int j = 0; j < 8; ++j) dst[(j << 8) + tid] = src[(j << 8) + tid];
  }

  // direct A-fragment loads: lane owns row llo (per m), k-slice lhi*8..+8 (per t);
  // convert f32->bf16 immediately to halve live registers
  bf16x8 af[2][4];
#pragma unroll
  for (int m = 0; m < 2; ++m) {
    int row = row0 + (wave << 5) + (m << 4) + llo;
    const float* rp = X + row * D + (lhi << 3);
    bool ok = row < N_NODES;
    float4 t0[4], t1[4];
#pragma unroll
    for (int t = 0; t < 4; ++t) {
      t0[t] = ok ? *(const float4*)(rp + (t << 5)) : make_float4(0.f, 0.f, 0.f, 0.f);
      t1[t] = ok ? *(const float4*)(rp + (t << 5) + 4) : make_float4(0.f, 0.f, 0.f, 0.f);
    }
#pragma unroll
    for (int t = 0; t < 4; ++t) {
      bf16x8 v;
      v[0] = (__bf16)t0[t].x; v[1] = (__bf16)t0[t].y; v[2] = (__bf16)t0[t].z; v[3] = (__bf16)t0[t].w;
      v[4] = (__bf16)t1[t].x; v[5] = (__bf16)t1[t].y; v[6] = (__bf16)t1[t].z; v[7] = (__bf16)t1[t].w;
      af[m][t] = v;
    }
  }
  __syncthreads();

  f32x4 acc[2][8];
#pragma unroll
  for (int m = 0; m < 2; ++m)
#pragma unroll
    for (int n = 0; n < 8; ++n)
      acc[m][n] = (f32x4){0.f, 0.f, 0.f, 0.f};

#pragma unroll
  for (int t = 0; t < 4; ++t) {
    const int k0 = (t << 5) + (lhi << 3);
    bf16x8 b[8];
#pragma unroll
    for (int n = 0; n < 8; ++n)
      b[n] = *(const bf16x8*)(Ws + swz((n << 4) + llo, k0));
#pragma unroll
    for (int m = 0; m < 2; ++m)
#pragma unroll
      for (int n = 0; n < 8; ++n)
        acc[m][n] = __builtin_amdgcn_mfma_f32_16x16x32_bf16(af[m][t], b[n], acc[m][n], 0, 0, 0);
  }

  // epilogue: C/D layout col=llo, row=lhi*4+r. Pack 8 cols (n=0..7) -> uint4 per (m,r).
#pragma unroll
  for (int m = 0; m < 2; ++m) {
#pragma unroll
    for (int r = 0; r < 4; ++r) {
      int row = row0 + (wave << 5) + (m << 4) + (lhi << 2) + r;
      if (row < N_NODES) {
        uint4 v;
        v.x = pk2(acc[m][0][r], acc[m][1][r]);
        v.y = pk2(acc[m][2][r], acc[m][3][r]);
        v.z = pk2(acc[m][4][r], acc[m][5][r]);
        v.w = pk2(acc[m][6][r], acc[m][7][r]);
        *(uint4*)(Xp + row * D + (llo << 3)) = v;
      }
    }
  }
}

// Kernel 2: out[i] = sum_{e} Xp[ci[e]]  (TWO rows per wave; Xp rows are col-permuted)
// Quarter-wave: group g=lane>>4 handles edges 4g..4g+3 of each row; lane j=lane&15
// loads 16 B (logical cols {n*16+j}). 8 uint4 gathers in flight per lane.
__global__ __launch_bounds__(256) void k_spmm(const ushort* __restrict__ Xp,
                                              const int* __restrict__ ci,
                                              float* __restrict__ out) {
  const int wave = threadIdx.x >> 6;
  const int lane = threadIdx.x & 63;
  const int row0 = (blockIdx.x << 3) + (wave << 1);   // wave handles row0, row0+1
  const int g = lane >> 4;
  const int j = lane & 15;

  // lanes 0..31 hold the 32 indices of both rows (contiguous in ci)
  int idx = 0;
  if (lane < 32) idx = __builtin_nontemporal_load(ci + row0 * DEG + lane);

  uint4 v0[4], v1[4];
#pragma unroll
  for (int e = 0; e < 4; ++e) {
    int c = __shfl(idx, (g << 2) + e);
    v0[e] = *(const uint4*)(Xp + c * D + (j << 3));
  }
#pragma unroll
  for (int e = 0; e < 4; ++e) {
    int c = __shfl(idx, 16 + (g << 2) + e);
    v1[e] = *(const uint4*)(Xp + c * D + (j << 3));
  }

  float a0[8], a1[8];
#pragma unroll
  for (int n = 0; n < 8; ++n) { a0[n] = 0.f; a1[n] = 0.f; }
#pragma unroll
  for (int e = 0; e < 4; ++e) {
    a0[0] += __uint_as_float(v0[e].x << 16);
    a0[1] += __uint_as_float(v0[e].x & 0xffff0000u);
    a0[2] += __uint_as_float(v0[e].y << 16);
    a0[3] += __uint_as_float(v0[e].y & 0xffff0000u);
    a0[4] += __uint_as_float(v0[e].z << 16);
    a0[5] += __uint_as_float(v0[e].z & 0xffff0000u);
    a0[6] += __uint_as_float(v0[e].w << 16);
    a0[7] += __uint_as_float(v0[e].w & 0xffff0000u);
    a1[0] += __uint_as_float(v1[e].x << 16);
    a1[1] += __uint_as_float(v1[e].x & 0xffff0000u);
    a1[2] += __uint_as_float(v1[e].y << 16);
    a1[3] += __uint_as_float(v1[e].y & 0xffff0000u);
    a1[4] += __uint_as_float(v1[e].z << 16);
    a1[5] += __uint_as_float(v1[e].z & 0xffff0000u);
    a1[6] += __uint_as_float(v1[e].w << 16);
    a1[7] += __uint_as_float(v1[e].w & 0xffff0000u);
  }

#pragma unroll
  for (int n = 0; n < 8; ++n) {
    a0[n] += __shfl_xor(a0[n], 16);
    a0[n] += __shfl_xor(a0[n], 32);
    a1[n] += __shfl_xor(a1[n], 16);
    a1[n] += __shfl_xor(a1[n], 32);
  }

  // lane (g,j): a[n] holds col n*16+j; store a[2g]->col 32g+j, a[2g+1]->col 32g+16+j
  float* op0 = out + row0 * D + (g << 5) + j;
  __builtin_nontemporal_store(a0[(g << 1)], op0);
  __builtin_nontemporal_store(a0[(g << 1) + 1], op0 + 16);
  float* op1 = op0 + D;
  __builtin_nontemporal_store(a1[(g << 1)], op1);
  __builtin_nontemporal_store(a1[(g << 1) + 1], op1 + 16);
}

extern "C" void kernel_launch(void* const* d_in, const int* in_sizes, int n_in,
                              void* d_out, int out_size, void* d_ws, size_t ws_size,
                              hipStream_t stream) {
  const float* X = (const float*)d_in[0];
  const float* W = (const float*)d_in[1];
  const int* ci = (const int*)d_in[3];

  ushort* Wt = (ushort*)d_ws;                 // 32 KB
  ushort* Xp = (ushort*)d_ws + 128 * 128;     // 25.6 MB bf16 X' (permuted rows)
  float* out = (float*)d_out;

  k_convW<<<64, 256, 0, stream>>>(W, Wt);
  k_gemm<<<(N_NODES + 127) / 128, 256, 0, stream>>>(X, Wt, Xp);
  k_spmm<<<N_NODES / 8, 256, 0, stream>>>(Xp, ci, out);
}